// Round 11
// baseline (3715.138 us; speedup 1.0000x reference)
//
#include <hip/hip_runtime.h>
#include <math.h>
#include <stdint.h>

#define HIDDEN 2048
#define TSTEPS 1024
#define NWG 256
#define TPB 512
#define UPW 8           // hidden units per WG
#define CPT 16          // columns per thread
#define FLAG_STRIDE 32  // ints per flag/go line (128 B)
#define GO_STRIDE 32
#define NXCD 8

__device__ __forceinline__ float sigmoidf_(float x) { return 1.0f / (1.0f + __expf(-x)); }

// sc0 load: bypass L1, serve from the XCD-shared L2.
__device__ __forceinline__ int load_sc0(const int* p) {
    int v;
    asm volatile("global_load_dword %0, %1, off sc0\n\t"
                 "s_waitcnt vmcnt(0)"
                 : "=v"(v) : "v"(p) : "memory");
    return v;
}
// sc0 store: write-through past L1 into the XCD L2 (the r9 bug was a plain
// write-back store that lingered in L1 — this is the mechanism under test).
__device__ __forceinline__ void store_sc0(int* p, int v) {
    asm volatile("global_store_dword %0, %1, off sc0" :: "v"(p), "v"(v) : "memory");
}

// v11 = v10 (one barrier/step, watcher + global go) + per-XCD sc0 relay fast path.
__global__ __launch_bounds__(TPB, 2)
void lstm_v11(const float* __restrict__ features,
              const float* __restrict__ pc,
              const float* __restrict__ W_ih,
              const float* __restrict__ W_hh,
              const float* __restrict__ b_ih,
              const float* __restrict__ b_hh,
              const float* __restrict__ W_fc,
              const float* __restrict__ b_fc,
              float* __restrict__ out,
              int*   __restrict__ flags,    // NWG lines, memset 0
              int*   __restrict__ go,       // 64 lines, memset 0 (agent path)
              int*   __restrict__ elect,    // NXCD lines, memset 0
              int*   __restrict__ go_local, // NXCD lines, memset 0 (sc0/L2 path)
              float* __restrict__ hhist)    // (TSTEPS+1)*HIDDEN floats
{
    const int b    = blockIdx.x;
    const int t    = threadIdx.x;
    const int lane = t & 63;
    const int wave = t >> 6;
    const int g    = t & 3;        // gate block 0..3 (i,f,g,o)
    const int cc   = t >> 2;       // column-chunk 0..127
    const int col0 = cc * CPT;
    const bool isw255 = (b == NWG - 1);

    // Invalidate caches across graph replays before any cached read of ws.
    __builtin_amdgcn_fence(__ATOMIC_ACQUIRE, "agent");

    // this WG's XCD (all waves of a WG share one CU -> one XCD)
    uint32_t xcdreg;
    asm volatile("s_getreg_b32 %0, hwreg(HW_REG_XCC_ID)" : "=s"(xcdreg));
    const int myxcd = (int)(xcdreg & (NXCD - 1));

    __shared__ float pc_sh[2 * TSTEPS];
    __shared__ float red[8 * 32];
    __shared__ float outred[16];
    __shared__ int   ls_go;        // WG 255 self-gate
    __shared__ int   ls_relay;     // this WG won the relay election for its XCD

    if (t == 0) {
        ls_go = 0;
        int won = 0;
        if (!isw255) {   // WG255's wave 7 is the global watcher; exclude from relay
            int expected = 0;
            won = __hip_atomic_compare_exchange_strong(
                      elect + (size_t)myxcd * GO_STRIDE, &expected, 1,
                      __ATOMIC_RELAXED, __ATOMIC_RELAXED, __HIP_MEMORY_SCOPE_AGENT)
                      ? 1 : 0;
        }
        ls_relay = won;
    }

    {   // point cloud -> LDS
        const float4* p4 = reinterpret_cast<const float4*>(pc);
        reinterpret_cast<float4*>(pc_sh)[t] = p4[t];
    }

    // W_hh slice -> registers: w[ji][k] = W_hh[g*2048 + b*8 + ji][col0 + k]
    float w[UPW][CPT];
    {
        const int baserow = g * HIDDEN + b * UPW;
        #pragma unroll
        for (int ji = 0; ji < UPW; ++ji) {
            const float4* src = reinterpret_cast<const float4*>(
                W_hh + (size_t)(baserow + ji) * HIDDEN + col0);
            float4 a0 = src[0], a1 = src[1], a2 = src[2], a3 = src[3];
            w[ji][0]  = a0.x; w[ji][1]  = a0.y; w[ji][2]  = a0.z; w[ji][3]  = a0.w;
            w[ji][4]  = a1.x; w[ji][5]  = a1.y; w[ji][6]  = a1.z; w[ji][7]  = a1.w;
            w[ji][8]  = a2.x; w[ji][9]  = a2.y; w[ji][10] = a2.z; w[ji][11] = a2.w;
            w[ji][12] = a3.x; w[ji][13] = a3.y; w[ji][14] = a3.z; w[ji][15] = a3.w;
        }
    }

    // per-row constants + cell state for wave 0 (row id l = lane&31: gate = l>>3, unit = l&7)
    float bias_r = 0.0f, wi0_r = 0.0f, wi1_r = 0.0f, creg = 0.0f;
    if (wave == 0) {
        const int l   = lane & 31;
        const int row = (l >> 3) * HIDDEN + b * UPW + (l & 7);
        bias_r = b_ih[row] + b_hh[row];
        wi0_r  = W_ih[row * 2 + 0];
        wi1_r  = W_ih[row * 2 + 1];
    }
    __syncthreads();   // covers pc_sh + ls_go/ls_relay init
    const bool relaywg = (ls_relay != 0);

    const int* gop = go + (size_t)(b >> 2) * GO_STRIDE;
    const int* lgp = go_local + (size_t)myxcd * GO_STRIDE;
    int*       lgs = go_local + (size_t)myxcd * GO_STRIDE;

    // ---- recurrence: ONE barrier per step ----
    for (int s = 0; s < TSTEPS; ++s) {
        const int rot = (s >= 1) && (b == ((s - 1) & 255));   // this WG emits out[s-1]

        // gate + load h_s
        float hr[CPT];
        if (s == 0) {
            #pragma unroll
            for (int k = 0; k < CPT; k += 4) {
                float4 hv = *reinterpret_cast<const float4*>(features + col0 + k);
                hr[k] = hv.x; hr[k + 1] = hv.y; hr[k + 2] = hv.z; hr[k + 3] = hv.w;
            }
        } else {
            if (isw255) {
                while (__hip_atomic_load(&ls_go, __ATOMIC_RELAXED,
                                         __HIP_MEMORY_SCOPE_WORKGROUP) < s) {}
            } else {
                // fast path: 3x sc0 poll of the XCD-local L2 line;
                // backstop: agent-scope global go line every 4th probe.
                for (;;) {
                    if (load_sc0(lgp) >= s) break;
                    if (load_sc0(lgp) >= s) break;
                    if (load_sc0(lgp) >= s) break;
                    if (__hip_atomic_load(gop, __ATOMIC_RELAXED,
                                          __HIP_MEMORY_SCOPE_AGENT) >= s) break;
                }
            }
            const float* hsrc = hhist + (size_t)s * HIDDEN;
            #pragma unroll
            for (int k = 0; k < CPT; k += 4) {
                float4 hv = *reinterpret_cast<const float4*>(hsrc + col0 + k);
                hr[k] = hv.x; hr[k + 1] = hv.y; hr[k + 2] = hv.z; hr[k + 3] = hv.w;
            }
        }

        // FMA phase
        float acc[UPW];
        #pragma unroll
        for (int ji = 0; ji < UPW; ++ji) acc[ji] = 0.0f;
        #pragma unroll
        for (int k = 0; k < CPT; ++k) {
            #pragma unroll
            for (int ji = 0; ji < UPW; ++ji) acc[ji] += w[ji][k] * hr[k];
        }
        #pragma unroll
        for (int m = 4; m < 64; m <<= 1) {
            #pragma unroll
            for (int ji = 0; ji < UPW; ++ji) acc[ji] += __shfl_xor(acc[ji], m);
        }
        if (lane < 4) {
            #pragma unroll
            for (int ji = 0; ji < UPW; ++ji) red[wave * 32 + lane * 8 + ji] = acc[ji];
        }

        // fc partials for out[s-1] (rotating WG; rides barrier (a))
        if (rot) {
            float po0 = 0.0f, po1 = 0.0f;
            #pragma unroll
            for (int k = 0; k < CPT; ++k) {
                po0 += hr[k] * W_fc[col0 + k];
                po1 += hr[k] * W_fc[HIDDEN + col0 + k];
            }
            #pragma unroll
            for (int m = 1; m < 64; m <<= 1) {
                po0 += __shfl_xor(po0, m);
                po1 += __shfl_xor(po1, m);
            }
            if (lane == 0) { outred[wave * 2 + 0] = po0; outred[wave * 2 + 1] = po1; }
        }
        __syncthreads();   // (a) red[] + outred[] ready

        if (wave == 0) {
            // final reduce + gates + publish (v6-identical)
            const int l = lane & 31;
            float sum = 0.0f;
            #pragma unroll
            for (int ww = 0; ww < 8; ++ww) sum += red[ww * 32 + l];
            const float x0 = pc_sh[2 * s], x1 = pc_sh[2 * s + 1];
            const float gate = sum + bias_r + wi0_r * x0 + wi1_r * x1;
            const float iv = __shfl(gate, (lane & 7));
            const float fv = __shfl(gate, 8 + (lane & 7));
            const float gv = __shfl(gate, 16 + (lane & 7));
            const float ov = __shfl(gate, 24 + (lane & 7));
            const float cnew = sigmoidf_(fv) * creg + sigmoidf_(iv) * tanhf(gv);
            const float hnew = sigmoidf_(ov) * tanhf(cnew);
            creg = cnew;   // lane tracks unit lane&7
            const uint32_t hb = __float_as_uint(hnew);

            // publish 8 floats as 4 write-through qword stores
            const uint32_t lo = __shfl(hb, 2 * (lane & 3));
            const uint32_t hi = __shfl(hb, 2 * (lane & 3) + 1);
            if (lane < 4) {
                const uint64_t qv = (uint64_t)lo | ((uint64_t)hi << 32);
                uint64_t* dst = reinterpret_cast<uint64_t*>(
                    hhist + (size_t)(s + 1) * HIDDEN + b * UPW) + lane;
                __hip_atomic_store(dst, qv, __ATOMIC_RELAXED, __HIP_MEMORY_SCOPE_AGENT);
            }
            // data acked at the coherence point before the flag becomes visible
            asm volatile("s_waitcnt vmcnt(0)" ::: "memory");
            if (lane == 0) {
                __hip_atomic_store(flags + (size_t)b * FLAG_STRIDE, s + 1,
                                   __ATOMIC_RELAXED, __HIP_MEMORY_SCOPE_AGENT);
            }
        }

        // global watcher: WG 255 wave 7 (v10-identical)
        if (isw255 && wave == 7) {
            const int l4 = lane * 4;
            const int* f0p = flags + (size_t)(l4 + 0) * FLAG_STRIDE;
            const int* f1p = flags + (size_t)(l4 + 1) * FLAG_STRIDE;
            const int* f2p = flags + (size_t)(l4 + 2) * FLAG_STRIDE;
            const int* f3p = flags + (size_t)(l4 + 3) * FLAG_STRIDE;
            for (;;) {
                const int f0 = __hip_atomic_load(f0p, __ATOMIC_RELAXED, __HIP_MEMORY_SCOPE_AGENT);
                const int f1 = __hip_atomic_load(f1p, __ATOMIC_RELAXED, __HIP_MEMORY_SCOPE_AGENT);
                const int f2 = __hip_atomic_load(f2p, __ATOMIC_RELAXED, __HIP_MEMORY_SCOPE_AGENT);
                const int f3 = __hip_atomic_load(f3p, __ATOMIC_RELAXED, __HIP_MEMORY_SCOPE_AGENT);
                const bool ok = (f0 >= s + 1) & (f1 >= s + 1) & (f2 >= s + 1) & (f3 >= s + 1);
                if (__all(ok)) break;
            }
            __hip_atomic_store(go + (size_t)lane * GO_STRIDE, s + 1,
                               __ATOMIC_RELAXED, __HIP_MEMORY_SCOPE_AGENT);
            if (lane == 0) {
                __hip_atomic_store(&ls_go, s + 1, __ATOMIC_RELAXED,
                                   __HIP_MEMORY_SCOPE_WORKGROUP);
            }
        }

        // per-XCD relay: elected WG's wave 7 — same detect, sc0 store to local L2
        if (relaywg && wave == 7) {
            const int l4 = lane * 4;
            const int* f0p = flags + (size_t)(l4 + 0) * FLAG_STRIDE;
            const int* f1p = flags + (size_t)(l4 + 1) * FLAG_STRIDE;
            const int* f2p = flags + (size_t)(l4 + 2) * FLAG_STRIDE;
            const int* f3p = flags + (size_t)(l4 + 3) * FLAG_STRIDE;
            for (;;) {
                const int f0 = __hip_atomic_load(f0p, __ATOMIC_RELAXED, __HIP_MEMORY_SCOPE_AGENT);
                const int f1 = __hip_atomic_load(f1p, __ATOMIC_RELAXED, __HIP_MEMORY_SCOPE_AGENT);
                const int f2 = __hip_atomic_load(f2p, __ATOMIC_RELAXED, __HIP_MEMORY_SCOPE_AGENT);
                const int f3 = __hip_atomic_load(f3p, __ATOMIC_RELAXED, __HIP_MEMORY_SCOPE_AGENT);
                const bool ok = (f0 >= s + 1) & (f1 >= s + 1) & (f2 >= s + 1) & (f3 >= s + 1);
                if (__all(ok)) break;
            }
            if (lane == 0) store_sc0(lgs, s + 1);
        }

        // out[s-1] final sum (outred valid since (a))
        if (rot && t == 64) {
            float o0 = 0.0f, o1 = 0.0f;
            #pragma unroll
            for (int ww = 0; ww < 8; ++ww) { o0 += outred[ww * 2]; o1 += outred[ww * 2 + 1]; }
            out[(s - 1) * 2 + 0] = 0.25f * o0 + b_fc[0];
            out[(s - 1) * 2 + 1] = 0.25f * o1 + b_fc[1];
        }
        // no barrier (b): go-gate at the top of the next iteration orders everything
    }

    // ---- epilogue: out[T-1] = fc(h_T); (T-1)&255 = 255 -> WG 255 ----
    if (isw255) {
        while (__hip_atomic_load(&ls_go, __ATOMIC_RELAXED,
                                 __HIP_MEMORY_SCOPE_WORKGROUP) < TSTEPS) {}
        const float* hsrc = hhist + (size_t)TSTEPS * HIDDEN;
        float po0 = 0.0f, po1 = 0.0f;
        #pragma unroll
        for (int k = 0; k < CPT; ++k) {
            const float hv = hsrc[col0 + k];
            po0 += hv * W_fc[col0 + k];
            po1 += hv * W_fc[HIDDEN + col0 + k];
        }
        #pragma unroll
        for (int m = 1; m < 64; m <<= 1) {
            po0 += __shfl_xor(po0, m);
            po1 += __shfl_xor(po1, m);
        }
        if (lane == 0) { outred[wave * 2 + 0] = po0; outred[wave * 2 + 1] = po1; }
        __syncthreads();
        if (t == 0) {
            float o0 = 0.0f, o1 = 0.0f;
            #pragma unroll
            for (int ww = 0; ww < 8; ++ww) { o0 += outred[ww * 2]; o1 += outred[ww * 2 + 1]; }
            out[(TSTEPS - 1) * 2 + 0] = 0.25f * o0 + b_fc[0];
            out[(TSTEPS - 1) * 2 + 1] = 0.25f * o1 + b_fc[1];
        }
    }
}

extern "C" void kernel_launch(void* const* d_in, const int* in_sizes, int n_in,
                              void* d_out, int out_size, void* d_ws, size_t ws_size,
                              hipStream_t stream) {
    const float* features = (const float*)d_in[0];
    const float* pc       = (const float*)d_in[1];
    const float* W_ih     = (const float*)d_in[2];
    const float* W_hh     = (const float*)d_in[3];
    const float* b_ih     = (const float*)d_in[4];
    const float* b_hh     = (const float*)d_in[5];
    const float* W_fc     = (const float*)d_in[6];
    const float* b_fc     = (const float*)d_in[7];
    float* out = (float*)d_out;

    const size_t flags_bytes = (size_t)NWG * FLAG_STRIDE * sizeof(int);   // 32 KB
    const size_t go_bytes    = (size_t)64 * GO_STRIDE * sizeof(int);      //  8 KB
    const size_t elect_bytes = (size_t)NXCD * GO_STRIDE * sizeof(int);    //  1 KB
    const size_t gol_bytes   = (size_t)NXCD * GO_STRIDE * sizeof(int);    //  1 KB
    const size_t hdr_bytes   = 65536;                                     // 64 KB aligned header

    int*   flags = (int*)d_ws;
    int*   go    = (int*)((char*)d_ws + flags_bytes);
    int*   elect = (int*)((char*)d_ws + flags_bytes + go_bytes);
    int*   go_l  = (int*)((char*)d_ws + flags_bytes + go_bytes + elect_bytes);
    float* hhist = (float*)((char*)d_ws + hdr_bytes);

    // all sync state must start at 0 every call (graph replays don't re-poison ws)
    hipMemsetAsync(d_ws, 0, flags_bytes + go_bytes + elect_bytes + gol_bytes, stream);

    hipLaunchKernelGGL(lstm_v11, dim3(NWG), dim3(TPB), 0, stream,
                       features, pc, W_ih, W_hh, b_ih, b_hh, W_fc, b_fc,
                       out, flags, go, elect, go_l, hhist);
}